// Round 13
// baseline (2428.798 us; speedup 1.0000x reference)
//
#include <hip/hip_runtime.h>

#define NOBS 2048
#define NX   128
#define NY   64
#define BS   8            // scenarios per solver block (256 blocks, 1/CU, all resident)
#define NT   1024         // 16 waves
#define NWAVE (NT / 64)
#define NITER 64

typedef short short8 __attribute__((ext_vector_type(8)));   // 8 bf16 (4 VGPRs)
typedef float f32x4 __attribute__((ext_vector_type(4)));    // MFMA accumulator
typedef unsigned short u16x4 __attribute__((ext_vector_type(4)));

// ---- bf16 split helpers (RNE) ----
__device__ __forceinline__ unsigned short bf16_rne(float x) {
    unsigned u = __float_as_uint(x);
    return (unsigned short)((u + 0x7FFFu + ((u >> 16) & 1u)) >> 16);
}
__device__ __forceinline__ float bf16_tof(unsigned short h) {
    return __uint_as_float(((unsigned)h) << 16);
}

// ---- DPP wave reduction (prep only) ----
template <int CTRL>
__device__ __forceinline__ float dpp_f(float x) {
    return __int_as_float(__builtin_amdgcn_update_dpp(
        0, __float_as_int(x), CTRL, 0xf, 0xf, true));
}
__device__ __forceinline__ float wave_sum64(float v) {
    v += dpp_f<0x111>(v);
    v += dpp_f<0x112>(v);
    v += dpp_f<0x114>(v);
    v += dpp_f<0x118>(v);
    v += dpp_f<0x142>(v);
    v += dpp_f<0x143>(v);   // lane 63 = total
    return v;
}

// ---- Kernel 1: Y_hat = X@W^T + b ; epsum ; ep bf16 3-way split, PACKED frags ----
// e = hi + md + lo + r, |r| <~ 2^-24 |e|.
// epT_pack[frag][16]: hi(8) | md(8)          (Phase C A-operand, rows=k, K=i)
// epA_pack[frag][24]: hi(8) | md(8) | lo(8)  (Phase A A-operand, rows=i, K=k)
__global__ __launch_bounds__(256) void prep_kernel(
    const float* __restrict__ X, const float* __restrict__ Y,
    const float* __restrict__ W, const float* __restrict__ b,
    float* __restrict__ yhat_out, float* __restrict__ epsum,
    unsigned short* __restrict__ epT_pack, unsigned short* __restrict__ epA_pack)
{
    __shared__ float Xs[4][NX];
    const int t = threadIdx.x;
    const int row0 = blockIdx.x * 4;
    for (int f = t; f < 4 * NX; f += 256)
        Xs[f >> 7][f & 127] = X[(row0 + (f >> 7)) * NX + (f & 127)];
    __syncthreads();

    const int k = t & 63;
    const int r = t >> 6;
    const float4* W4 = reinterpret_cast<const float4*>(W + k * NX);
    const float4* X4 = reinterpret_cast<const float4*>(&Xs[r][0]);
    float acc = 0.f;
    #pragma unroll
    for (int x = 0; x < NX / 4; ++x) {
        float4 wv = W4[x];
        float4 xv = X4[x];
        acc += wv.x * xv.x + wv.y * xv.y + wv.z * xv.z + wv.w * xv.w;
    }
    const float yh = acc + b[k];
    const int i = row0 + r;
    yhat_out[i * NY + k] = yh;
    const float e = Y[i * NY + k] - yh;

    const unsigned short hi = bf16_rne(e);
    const float r1 = e - bf16_tof(hi);
    const unsigned short md = bf16_rne(r1);
    const unsigned short lo = bf16_rne(r1 - bf16_tof(md));
    // Phase C frag (rows = k, K = i):  A[row=lane&15][kk=8*(lane>>4)+d]
    {
        const int m  = k >> 4;
        const int q  = i >> 5;
        const int lc = (k & 15) + 16 * ((i >> 3) & 3);
        const int d  = i & 7;
        const int fT = (m * 64 + q) * 64 + lc;
        epT_pack[fT * 16 + d]     = hi;
        epT_pack[fT * 16 + 8 + d] = md;
    }
    // Phase A frag (rows = i, K = k)
    {
        const int m  = i >> 4;
        const int q  = k >> 5;
        const int lc = (i & 15) + 16 * ((k >> 3) & 3);
        const int d  = k & 7;
        const int fA = (m * 2 + q) * 64 + lc;
        epA_pack[fA * 24 + d]      = hi;
        epA_pack[fA * 24 + 8 + d]  = md;
        epA_pack[fA * 24 + 16 + d] = lo;
    }

    float se = wave_sum64(e);
    if ((t & 63) == 63) atomicAdd(epsum, se);
}

// ---- Kernel 2: batched projected-subgradient DRO solve ----
// Phase A on MFMA (3-way split, 6 terms, EIGHT passes of ONE m-tile each,
// acc streamed straight to LDS); Phase C on MFMA (2-way, 3 terms). 5 barriers.
// Anti-spill (R7-R12): the compiler gives this 1024-thread kernel 64 arch
// VGPRs no matter what; any spill puts scratch in the L2 working set
// (~3-6 MB/XCD for ~100 B/thread), thrashing the 4-MB L2 -> ep re-fetches
// every iter (R12: 6 GB FETCH = the entire runtime at 2.6 TB/s; R5 no-spill:
// 9.6 MB). Demand must fit 64: one m-tile per pass caps in-flight state at
// acc(4) + z-frags(12) + A-frags(12) + addressing (~6).
__global__ __launch_bounds__(NT)
__attribute__((amdgpu_waves_per_eu(4, 4)))
void solve_kernel(
    const float* __restrict__ yhat, const float* __restrict__ epsum,
    const float* __restrict__ rho_p,
    const unsigned short* __restrict__ epT_pack,
    const unsigned short* __restrict__ epA_pack,
    float* __restrict__ zout)
{
    __shared__ float Zs[BS][NY];                 // 2 KB
    __shared__ float Yh[BS][NY];                 // 2 KB
    __shared__ unsigned short VT_hi[BS][2056];   // 32.1 KB
    __shared__ unsigned short VT_lo[BS][2056];   // 32.1 KB
    __shared__ __align__(16) unsigned short Zb_hi[16][72];  // 2.25 KB (cols 8..15 dup)
    __shared__ __align__(16) unsigned short Zb_md[16][72];  // 2.25 KB
    __shared__ __align__(16) unsigned short Zb_lo[16][72];  // 2.25 KB
    __shared__ float Rp2[4][4][64][4];           // 16 KB  [g][m][lane][reg]
    __shared__ float4 Sbuf[NWAVE][4][64];        // 64 KB  per-thread raw-acc stash
    __shared__ float redM[NWAVE][BS];            // per-wave umax partials
    __shared__ float red2[NWAVE][BS][4];         // per-wave {pa,pe,pas,pes}
    __shared__ float cS[16], lamS[16];           // cols 8..15 dup
    __shared__ __align__(16) unsigned short zb[8];

    const int t = threadIdx.x;
    const int lane = t & 63;
    const int wv = t >> 6;
    const int jb = lane & 15;      // MFMA column
    const int h  = lane >> 4;      // frag k-chunk / row-group
    const int j8 = jb & 7;         // actual scenario
    const bool hiHalf = (jb >= 8);
    const int sc0 = blockIdx.x * BS;
    const float rho = rho_p[0];

    if (t < BS * NY) {
        const int j = t >> 6, k = t & 63;
        Yh[j][k] = yhat[(sc0 + j) * NY + k];
        Zs[j][k] = 1.0f / 64.0f;
    }
    {   // z0 = 1/64 exact in bf16 (power of two) -> md = lo = 0
        const int j = t >> 6, k = t & 63;
        Zb_hi[j][k] = bf16_rne(1.0f / 64.0f);
        Zb_md[j][k] = 0;
        Zb_lo[j][k] = 0;
    }
    if (t < 16) {
        cS[t] = epsum[0] * (1.0f / 131072.0f);  // mean(ep) == mean(ep @ z0)
        lamS[t] = 1.0f;
    }
    if (t < 8) zb[t] = 0;
    __syncthreads();

    for (int it = 0; it < NITER; ++it) {
        const float lr = 0.05f / sqrtf((float)it + 1.0f);

        const float cR = cS[jb];
        const float lm = lamS[jb];

        // ---- Phase A: raw S-partials via MFMA, 6-term 3-way split, 8 passes ----
        // pass p = m-tile p; lo-half lanes keep passes 0-3 (n = p&3),
        // hi-half keep 4-7. acc goes straight to Sbuf (no register array).
        #pragma unroll
        for (int pass = 0; pass < 8; ++pass) {
            f32x4 acc = {0.f, 0.f, 0.f, 0.f};
            #pragma unroll
            for (int q = 0; q < 2; ++q) {
                const short8 zh = *(const short8*)&Zb_hi[jb][(q << 5) + (h << 3)];
                const short8 zm = *(const short8*)&Zb_md[jb][(q << 5) + (h << 3)];
                const short8 zl = *(const short8*)&Zb_lo[jb][(q << 5) + (h << 3)];
                const unsigned short* pb = epA_pack
                    + (size_t)((((wv << 3) + pass) * 2 + q) * 64 + lane) * 24;
                const short8 ah = *(const short8*)(pb);
                const short8 am = *(const short8*)(pb + 8);
                const short8 al = *(const short8*)(pb + 16);
                acc = __builtin_amdgcn_mfma_f32_16x16x32_bf16(al, zh, acc, 0, 0, 0); // lH
                acc = __builtin_amdgcn_mfma_f32_16x16x32_bf16(ah, zl, acc, 0, 0, 0); // hL
                acc = __builtin_amdgcn_mfma_f32_16x16x32_bf16(am, zm, acc, 0, 0, 0); // mM
                acc = __builtin_amdgcn_mfma_f32_16x16x32_bf16(am, zh, acc, 0, 0, 0); // mH
                acc = __builtin_amdgcn_mfma_f32_16x16x32_bf16(ah, zm, acc, 0, 0, 0); // hM
                acc = __builtin_amdgcn_mfma_f32_16x16x32_bf16(ah, zh, acc, 0, 0, 0); // hH
            }
            const bool take = hiHalf ? (pass >= 4) : (pass < 4);
            if (take)
                Sbuf[wv][pass & 3][lane] = make_float4(acc[0], acc[1], acc[2], acc[3]);
            __builtin_amdgcn_sched_barrier(0);   // no cross-pass load hoisting
        }

        // ---- Phase B1: per-wave umax (read Sbuf, s = acc - cR; u = s*s) ----
        float pm = 0.f;
        #pragma unroll
        for (int n = 0; n < 4; ++n) {
            const float4 s4 = Sbuf[wv][n][lane];
            const float sarr[4] = {s4.x, s4.y, s4.z, s4.w};
            #pragma unroll
            for (int p = 0; p < 4; ++p) {
                const float ss = sarr[p] - cR;
                pm = fmaxf(pm, ss * ss);
            }
        }
        pm = fmaxf(pm, __shfl_xor(pm, 8, 64));
        pm = fmaxf(pm, __shfl_xor(pm, 16, 64));
        pm = fmaxf(pm, __shfl_xor(pm, 32, 64));
        if (lane < 8) redM[wv][lane] = pm;
        __syncthreads();   // bar 1

        // ---- umax fold (all lanes) ----
        float um = redM[0][j8];
        #pragma unroll
        for (int w = 1; w < NWAVE; ++w) um = fmaxf(um, redM[w][j8]);

        // ---- Phase B2: sums of a, eq, a*s, eq*s (JAX balanced-tie semantics) ----
        float pa = 0.f, pe = 0.f, pas = 0.f, pes = 0.f;
        #pragma unroll
        for (int n = 0; n < 4; ++n) {
            const float4 s4 = Sbuf[wv][n][lane];
            const float sarr[4] = {s4.x, s4.y, s4.z, s4.w};
            #pragma unroll
            for (int p = 0; p < 4; ++p) {
                const float ss = sarr[p] - cR, u = ss * ss;
                const float x = (u - um) + lm;
                const float a = (x > -lm) ? 1.0f : ((x == -lm) ? 0.5f : 0.0f);
                const float e = (u == um) ? 1.0f : 0.0f;
                pa += a; pe += e; pas += a * ss; pes += e * ss;
            }
        }
        pa  += __shfl_xor(pa, 8, 64);  pa  += __shfl_xor(pa, 16, 64);  pa  += __shfl_xor(pa, 32, 64);
        pe  += __shfl_xor(pe, 8, 64);  pe  += __shfl_xor(pe, 16, 64);  pe  += __shfl_xor(pe, 32, 64);
        pas += __shfl_xor(pas, 8, 64); pas += __shfl_xor(pas, 16, 64); pas += __shfl_xor(pas, 32, 64);
        pes += __shfl_xor(pes, 8, 64); pes += __shfl_xor(pes, 16, 64); pes += __shfl_xor(pes, 32, 64);
        if (lane < 8) {
            f32x4 r4 = {pa, pe, pas, pes};
            *(f32x4*)&red2[wv][lane][0] = r4;
        }
        __syncthreads();   // bar 2

        // ---- sum fold (all lanes, b128 broadcast reads); c/lam update by wave 0 ----
        float sA = 0.f, sE = 0.f, sAS = 0.f, sES = 0.f;
        #pragma unroll
        for (int w = 0; w < NWAVE; ++w) {
            const f32x4 rr = *(const f32x4*)&red2[w][j8][0];
            sA += rr[0]; sE += rr[1]; sAS += rr[2]; sES += rr[3];
        }
        const float abar = sA * (1.0f / (float)NOBS);
        const float wA = (1.0f - abar) / sE;      // argmax weight / tie count
        const float gc = -2.0f * (sAS * (1.0f / (float)NOBS) + wA * sES);
        const float glam = (rho - 2.0f) + 2.0f * abar;
        if (wv == 0 && lane < 16) {               // consumed next iteration (after bar 5)
            cS[lane] = cS[lane] - lr * gc;
            lamS[lane] = fmaxf(lamS[lane] - lr * glam, 0.0f);
        }

        // ---- Phase B4: v = (a/n + eq*wA) * s -> bf16 hi/lo packed b64 into VT ----
        #pragma unroll
        for (int n = 0; n < 4; ++n) {
            const float4 s4 = Sbuf[wv][n][lane];
            const float sarr[4] = {s4.x, s4.y, s4.z, s4.w};
            u16x4 vh4, vl4;
            #pragma unroll
            for (int p = 0; p < 4; ++p) {
                const float ss = sarr[p] - cR, u = ss * ss;
                const float x = (u - um) + lm;
                const float a = (x > -lm) ? 1.0f : ((x == -lm) ? 0.5f : 0.0f);
                const float e = (u == um) ? 1.0f : 0.0f;
                const float vv = (a * (1.0f / (float)NOBS) + e * wA) * ss;
                const unsigned short vhh = bf16_rne(vv);
                vh4[p] = vhh;
                vl4[p] = bf16_rne(vv - bf16_tof(vhh));
            }
            const int ii = ((wv << 3) + (hiHalf ? 4 : 0) + n) * 16 + (h << 2);
            *(u16x4*)&VT_hi[j8][ii] = vh4;
            *(u16x4*)&VT_lo[j8][ii] = vl4;
        }
        __syncthreads();   // bar 3

        // ---- Phase C: r = ep^T v via MFMA, 3-term 2-way split (R5-proven) ----
        {
            const int m = wv & 3;
            const int g = wv >> 2;
            f32x4 accC = {0.f, 0.f, 0.f, 0.f};
            #pragma unroll 4
            for (int qq = 0; qq < 16; ++qq) {
                const int q = g * 16 + qq;
                const unsigned short* pb = epT_pack
                    + (size_t)((m * 64 + q) * 64 + lane) * 16;
                const short8 ah = *(const short8*)(pb);
                const short8 al = *(const short8*)(pb + 8);
                const unsigned short* vh = (!hiHalf) ? &VT_hi[jb][(q << 5) + (h << 3)] : zb;
                const unsigned short* vl = (!hiHalf) ? &VT_lo[jb][(q << 5) + (h << 3)] : zb;
                const short8 bh = *(const short8*)vh;
                const short8 bl = *(const short8*)vl;
                accC = __builtin_amdgcn_mfma_f32_16x16x32_bf16(al, bh, accC, 0, 0, 0);
                accC = __builtin_amdgcn_mfma_f32_16x16x32_bf16(ah, bl, accC, 0, 0, 0);
                accC = __builtin_amdgcn_mfma_f32_16x16x32_bf16(ah, bh, accC, 0, 0, 0);
            }
            *(f32x4*)(&Rp2[g][m][lane][0]) = accC;
        }
        __syncthreads();   // bar 4

        // ---- Phase D: fold Rp2; update + simplex projection (wave j); z -> 3-way split ----
        if (wv < BS) {
            const int j = wv, k = lane;
            const int m = k >> 4, p = k & 3, ll = ((k >> 2) & 3) * 16 + j;
            const float r = Rp2[0][m][ll][p] + Rp2[1][m][ll][p]
                          + Rp2[2][m][ll][p] + Rp2[3][m][ll][p];
            const float gz = 2.0f * r - Yh[j][k];
            const float vz = Zs[j][k] - lr * gz;

            // bitonic sort (descending) across 64 lanes
            float sv2 = vz;
            #pragma unroll
            for (int sz = 2; sz <= 64; sz <<= 1) {
                #pragma unroll
                for (int st = sz >> 1; st > 0; st >>= 1) {
                    const float other = __shfl_xor(sv2, st, 64);
                    const bool desc = ((lane & sz) == 0);
                    const bool lower = ((lane & st) == 0);
                    const float mx = fmaxf(sv2, other), mn = fminf(sv2, other);
                    sv2 = (lower == desc) ? mx : mn;
                }
            }
            // inclusive scan -> cumsum - 1
            float css = sv2;
            #pragma unroll
            for (int off = 1; off < 64; off <<= 1) {
                const float nb = __shfl_up(css, off, 64);
                if (lane >= off) css += nb;
            }
            css -= 1.0f;
            const bool cond = (sv2 - css / (float)(lane + 1)) > 0.0f;
            const unsigned long long bal = __ballot(cond);
            const int idx = __popcll(bal) - 1;
            const float cssIdx = __shfl(css, idx, 64);
            const float theta = cssIdx / (float)(idx + 1);
            const float zk = fmaxf(vz - theta, 0.0f);
            Zs[j][k] = zk;
            const unsigned short zh_ = bf16_rne(zk);
            const float zr1 = zk - bf16_tof(zh_);
            const unsigned short zm_ = bf16_rne(zr1);
            const unsigned short zl_ = bf16_rne(zr1 - bf16_tof(zm_));
            Zb_hi[j][k] = zh_; Zb_hi[j + 8][k] = zh_;   // duplicate into cols 8..15
            Zb_md[j][k] = zm_; Zb_md[j + 8][k] = zm_;
            Zb_lo[j][k] = zl_; Zb_lo[j + 8][k] = zl_;
        }
        __syncthreads();   // bar 5
    }

    if (t < BS * NY) {
        const int j = t >> 6, k = t & 63;
        zout[(sc0 + j) * NY + k] = Zs[j][k];
    }
}

extern "C" void kernel_launch(void* const* d_in, const int* in_sizes, int n_in,
                              void* d_out, int out_size, void* d_ws, size_t ws_size,
                              hipStream_t stream) {
    const float* X   = (const float*)d_in[0];
    const float* Y   = (const float*)d_in[1];
    const float* rho = (const float*)d_in[2];
    const float* W   = (const float*)d_in[3];
    const float* b   = (const float*)d_in[4];

    float* out   = (float*)d_out;
    float* zout  = out;                 // Z_star: 2048*64
    float* yhat  = out + NOBS * NY;     // Y_hat:  2048*64

    // workspace: epT_pack (512 KB) | epA_pack (768 KB) | epsum (4 B)
    unsigned short* epT_pack = (unsigned short*)d_ws;            // 2048*64*2 shorts
    unsigned short* epA_pack = epT_pack + NY * NOBS * 2;         // 2048*64*3 shorts
    float* epsum = (float*)(epA_pack + NY * NOBS * 3);           // 1 f32

    hipMemsetAsync(epsum, 0, sizeof(float), stream);
    prep_kernel<<<NOBS / 4, 256, 0, stream>>>(X, Y, W, b, yhat, epsum,
                                              epT_pack, epA_pack);
    solve_kernel<<<NOBS / BS, NT, 0, stream>>>(yhat, epsum, rho,
                                               epT_pack, epA_pack, zout);
}